// Round 4
// baseline (200.522 us; speedup 1.0000x reference)
//
#include <hip/hip_runtime.h>
#include <math.h>

typedef unsigned short ushort_t;
typedef __attribute__((ext_vector_type(8))) short bf16x8_t;
typedef __attribute__((ext_vector_type(4))) float f32x4_t;

// ---------------- split helpers ----------------
// Truncation split: hi = trunc16(v), lo = trunc16(v - hi); |err| <= 2^-16 |v|.
__device__ __forceinline__ void tsplit(float v, unsigned& h, unsigned& l) {
  unsigned u = __float_as_uint(v);
  h = u >> 16;
  float lo = v - __uint_as_float(u & 0xffff0000u);
  l = __float_as_uint(lo) >> 16;
}

// split 8 fp32 -> hi/lo bf16x8 fragments (k-contiguous packing)
__device__ __forceinline__ void split8(const float* p, bf16x8_t& hi, bf16x8_t& lo) {
#pragma unroll
  for (int e = 0; e < 8; ++e) {
    unsigned h, l;
    tsplit(p[e], h, l);
    hi[e] = (short)h;
    lo[e] = (short)l;
  }
}

#define LSTR 40

// ---------------- gemm1: h = silu(x @ W1 + b1) -> hh/hl ----------------
// R1-proven structure: 512 threads, 8 waves (2m x 4n of 16x16), tile 32m x
// 64n, K=1024, BK=32. Staging splits/transposes fp32 inputs in registers:
//   waves 0-1: x tile, waves 2-5: W1 tile (coalesced across 64 n per instr),
//   waves 6-7: idle during stage. No reg-prefetch.
__global__ __launch_bounds__(512) void gemm1_kernel(
    const float* __restrict__ x, const float* __restrict__ W1,
    const float* __restrict__ b1,
    ushort_t* __restrict__ hh, ushort_t* __restrict__ hl) {
  __shared__ __align__(16) ushort_t As[2][32 * LSTR];
  __shared__ __align__(16) ushort_t Bs[2][64 * LSTR];
  const int t = threadIdx.x;
  const int lane = t & 63;
  const int wv = t >> 6;          // 0..7
  const int l15 = lane & 15;
  const int quad = lane >> 4;
  const int wm = wv & 1;          // m half (16 rows)
  const int wn = wv >> 1;         // n strip (16 cols)
  const int m0 = (blockIdx.x >> 5) * 32;
  const int n0 = (blockIdx.x & 31) * 64;

  f32x4_t acc = (f32x4_t){0.f, 0.f, 0.f, 0.f};

  // staging roles
  const int xrow = (t & 127) >> 2;     // waves 0-1: 32 rows
  const int xkq  = (t & 3) * 8;        // 8 consecutive k
  const int wu   = t - 128;            // waves 2-5: W1
  const int wnx  = wu & 63;            // n within tile
  const int wkh  = (wu >> 6) & 3;      // k-octet 0..3
  const bool wok = (n0 + wnx) < 2047;

  for (int k0 = 0; k0 < 1024; k0 += 32) {
    if (t < 128) {
      const float* src = x + (size_t)(m0 + xrow) * 1024 + k0 + xkq;
      float p[8];
      float4 va = *(const float4*)src;
      float4 vb = *(const float4*)(src + 4);
      p[0] = va.x; p[1] = va.y; p[2] = va.z; p[3] = va.w;
      p[4] = vb.x; p[5] = vb.y; p[6] = vb.z; p[7] = vb.w;
      bf16x8_t hi, lo;
      split8(p, hi, lo);
      *(bf16x8_t*)&As[0][xrow * LSTR + xkq] = hi;
      *(bf16x8_t*)&As[1][xrow * LSTR + xkq] = lo;
    } else if (t < 384) {
      float p[8];
#pragma unroll
      for (int i = 0; i < 8; ++i) {
        int k = k0 + wkh * 8 + i;     // k < 1024 always
        p[i] = wok ? W1[(size_t)k * 2047 + n0 + wnx] : 0.f;
      }
      bf16x8_t hi, lo;
      split8(p, hi, lo);
      *(bf16x8_t*)&Bs[0][wnx * LSTR + wkh * 8] = hi;
      *(bf16x8_t*)&Bs[1][wnx * LSTR + wkh * 8] = lo;
    }
    __syncthreads();
    const int nr = wn * 16 + l15;
    bf16x8_t bfh = *(const bf16x8_t*)&Bs[0][nr * LSTR + quad * 8];
    bf16x8_t bfl = *(const bf16x8_t*)&Bs[1][nr * LSTR + quad * 8];
    const int mr = wm * 16 + l15;
    bf16x8_t afh = *(const bf16x8_t*)&As[0][mr * LSTR + quad * 8];
    bf16x8_t afl = *(const bf16x8_t*)&As[1][mr * LSTR + quad * 8];
    acc = __builtin_amdgcn_mfma_f32_16x16x32_bf16(afh, bfh, acc, 0, 0, 0);
    acc = __builtin_amdgcn_mfma_f32_16x16x32_bf16(afh, bfl, acc, 0, 0, 0);
    acc = __builtin_amdgcn_mfma_f32_16x16x32_bf16(afl, bfh, acc, 0, 0, 0);
    __syncthreads();
  }
  // epilogue: bias + silu + split -> hh/hl (col 2047 = 0 pad)
  const int col = n0 + wn * 16 + l15;
#pragma unroll
  for (int rg = 0; rg < 4; ++rg) {
    int row = m0 + wm * 16 + quad * 4 + rg;
    float v = acc[rg];
    if (col < 2047) {
      v += b1[col];
      v = v / (1.f + expf(-v));
    } else {
      v = 0.f;
    }
    unsigned h, l;
    tsplit(v, h, l);
    size_t o = (size_t)row * 2048 + col;
    hh[o] = (ushort_t)h;
    hl[o] = (ushort_t)l;
  }
}

// ---------------- GEMM2: 64m x 64n tile, split-K=4, BK=32, 2-phase -------
// R4 change vs R3: LDS double-buffer (2 x 20 KB, 4 blocks/CU = full 160 KiB)
// + register prefetch of tile kt+1 issued right after the single per-iter
// barrier, hiding global-load latency under the MFMA phase. Barriers 32->16.
// Prefetch arrays are 16 VGPR per role (4x int4 / 16x fp32, static indexing)
// -- sized to avoid R2's scratch spill. LDS contents and MFMA order are
// bit-identical to R3.
__global__ __launch_bounds__(256) void gemm2k_kernel(
    const ushort_t* __restrict__ Ah, const ushort_t* __restrict__ Al,
    const float* __restrict__ W2,
    float* __restrict__ part) {
  __shared__ __align__(16) ushort_t Ab[2][2][64 * LSTR];
  __shared__ __align__(16) ushort_t Bb[2][2][64 * LSTR];
  const int t = threadIdx.x;
  const int lane = t & 63;
  const int wv = t >> 6;
  const int l15 = lane & 15;
  const int quad = lane >> 4;
  const int wm = wv >> 1, wn = wv & 1;
  const int m0 = blockIdx.y * 64;
  const int n0 = blockIdx.x * 64;
  const int ks = blockIdx.z;

  const int wu  = t - 128;          // waves 2-3: W2 stage
  const int bn  = wu & 63;          // n within tile
  const int bkh = (wu >> 6) & 1;    // k-half (16 k)
  const bool bok = (n0 + bn) < 4095;
  const int ar  = lane >> 2;        // A stage: row within 16-row group
  const int ac  = (lane & 3) * 8;   // A stage: 8-ushort column chunk

  f32x4_t acc[2][2];
#pragma unroll
  for (int i = 0; i < 2; ++i)
#pragma unroll
    for (int j = 0; j < 2; ++j) acc[i][j] = (f32x4_t){0.f, 0.f, 0.f, 0.f};

  int4  pa[4];     // waves 0-1: A prefetch (16 VGPR)
  float pw[16];    // waves 2-3: W2 prefetch (16 VGPR)

  // prologue: load k-tile 0 into regs
  {
    const int k0 = ks * 512;
    if (wv < 2) {
      const ushort_t* src = wv ? Al : Ah;
#pragma unroll
      for (int q = 0; q < 4; ++q)
        pa[q] = *(const int4*)(src + (size_t)(m0 + q * 16 + ar) * 2048 + k0 + ac);
    } else {
#pragma unroll
      for (int i = 0; i < 16; ++i) {
        int k = k0 + bkh * 16 + i;
        pw[i] = (bok && k < 2047) ? W2[(size_t)k * 4095 + n0 + bn] : 0.f;
      }
    }
  }

  int cur = 0;
  for (int kt = 0; kt < 16; ++kt) {
    // write current regs -> LDS[cur]
    if (wv < 2) {
      ushort_t* dst = Ab[cur][wv];
#pragma unroll
      for (int q = 0; q < 4; ++q)
        *(int4*)&dst[(q * 16 + ar) * LSTR + ac] = pa[q];
    } else {
#pragma unroll
      for (int half = 0; half < 2; ++half) {
        bf16x8_t hi, lo;
        split8(&pw[half * 8], hi, lo);
        *(bf16x8_t*)&Bb[cur][0][bn * LSTR + bkh * 16 + half * 8] = hi;
        *(bf16x8_t*)&Bb[cur][1][bn * LSTR + bkh * 16 + half * 8] = lo;
      }
    }
    __syncthreads();   // single barrier per iteration (dbuf makes it safe)
    // prefetch next k-tile into regs; latency hides under MFMA below
    if (kt + 1 < 16) {
      const int k0 = ks * 512 + (kt + 1) * 32;
      if (wv < 2) {
        const ushort_t* src = wv ? Al : Ah;
#pragma unroll
        for (int q = 0; q < 4; ++q)
          pa[q] = *(const int4*)(src + (size_t)(m0 + q * 16 + ar) * 2048 + k0 + ac);
      } else {
#pragma unroll
        for (int i = 0; i < 16; ++i) {
          int k = k0 + bkh * 16 + i;
          pw[i] = (bok && k < 2047) ? W2[(size_t)k * 4095 + n0 + bn] : 0.f;
        }
      }
    }
    // MFMA from LDS[cur] (order identical to R3)
    bf16x8_t bfh[2], bfl[2];
#pragma unroll
    for (int j = 0; j < 2; ++j) {
      int nr = wn * 32 + j * 16 + l15;
      bfh[j] = *(const bf16x8_t*)&Bb[cur][0][nr * LSTR + quad * 8];
      bfl[j] = *(const bf16x8_t*)&Bb[cur][1][nr * LSTR + quad * 8];
    }
#pragma unroll
    for (int i = 0; i < 2; ++i) {
      int mr = wm * 32 + i * 16 + l15;
      bf16x8_t afh = *(const bf16x8_t*)&Ab[cur][0][mr * LSTR + quad * 8];
      bf16x8_t afl = *(const bf16x8_t*)&Ab[cur][1][mr * LSTR + quad * 8];
#pragma unroll
      for (int j = 0; j < 2; ++j) {
        acc[i][j] = __builtin_amdgcn_mfma_f32_16x16x32_bf16(
            afh, bfh[j], acc[i][j], 0, 0, 0);
        acc[i][j] = __builtin_amdgcn_mfma_f32_16x16x32_bf16(
            afh, bfl[j], acc[i][j], 0, 0, 0);
        acc[i][j] = __builtin_amdgcn_mfma_f32_16x16x32_bf16(
            afl, bfh[j], acc[i][j], 0, 0, 0);
      }
    }
    cur ^= 1;
  }
  float* pbase = part + (size_t)ks * 256 * 4096;
#pragma unroll
  for (int i = 0; i < 2; ++i)
#pragma unroll
    for (int j = 0; j < 2; ++j) {
      int row0 = m0 + wm * 32 + i * 16 + quad * 4;
      int col = n0 + wn * 32 + j * 16 + l15;
#pragma unroll
      for (int rg = 0; rg < 4; ++rg)
        pbase[(size_t)(row0 + rg) * 4096 + col] = acc[i][j][rg];
    }
}

// ---------------- fallback fp32 GEMM (round-1, known-good) ----------------
#define TM 64
#define TN 64
#define TK 16
__global__ __launch_bounds__(256) void gemm_tiled(
    const float* __restrict__ X, const float* __restrict__ W,
    const float* __restrict__ bias, float* __restrict__ out,
    int M, int N, int K, int ldx, int ldw, int ldo, int doSilu, int padN)
{
  __shared__ float Xs[TK][TM + 4];
  __shared__ float Ws[TK][TN + 4];
  const int t = threadIdx.x;
  const int n0 = blockIdx.x * TN;
  const int m0 = blockIdx.y * TM;
  const int tr = t >> 4, tc = t & 15;
  float acc[4][4];
#pragma unroll
  for (int i = 0; i < 4; ++i)
#pragma unroll
    for (int j = 0; j < 4; ++j) acc[i][j] = 0.f;
  const int xr = t >> 2, xk = (t & 3) * 4;
  const int wk = t >> 4, wc = (t & 15) * 4;
  for (int k0 = 0; k0 < K; k0 += TK) {
    {
      const float* xp = X + (size_t)(m0 + xr) * ldx + (k0 + xk);
      float xv[4];
      if (k0 + xk + 3 < K) {
        float4 v = *(const float4*)xp;
        xv[0] = v.x; xv[1] = v.y; xv[2] = v.z; xv[3] = v.w;
      } else {
#pragma unroll
        for (int e = 0; e < 4; ++e) xv[e] = (k0 + xk + e < K) ? xp[e] : 0.f;
      }
#pragma unroll
      for (int e = 0; e < 4; ++e) Xs[xk + e][xr] = xv[e];
    }
    {
      const int kk = k0 + wk;
      const float* wp = W + (size_t)kk * ldw + (n0 + wc);
      const bool kv = kk < K;
#pragma unroll
      for (int e = 0; e < 4; ++e) {
        int n = n0 + wc + e;
        Ws[wk][wc + e] = (kv && n < N) ? wp[e] : 0.f;
      }
    }
    __syncthreads();
#pragma unroll
    for (int k = 0; k < TK; ++k) {
      float4 av = *(const float4*)&Xs[k][tr * 4];
      float4 bv = *(const float4*)&Ws[k][tc * 4];
      float a4[4] = {av.x, av.y, av.z, av.w};
      float b4[4] = {bv.x, bv.y, bv.z, bv.w};
#pragma unroll
      for (int i = 0; i < 4; ++i)
#pragma unroll
        for (int j = 0; j < 4; ++j)
          acc[i][j] = fmaf(a4[i], b4[j], acc[i][j]);
    }
    __syncthreads();
  }
#pragma unroll
  for (int i = 0; i < 4; ++i) {
    const int mrow = m0 + tr * 4 + i;
    float* op = out + (size_t)mrow * ldo;
#pragma unroll
    for (int j = 0; j < 4; ++j) {
      const int n = n0 + tc * 4 + j;
      if (n < N) {
        float v = acc[i][j] + bias[n];
        if (doSilu) v = v / (1.f + expf(-v));
        op[n] = v;
      } else if (n < padN) {
        op[n] = 0.f;
      }
    }
  }
}

// ---------------- quantum pipeline: 1024 threads, 16 waves, 1 tile/wave ----
#define RS 72
#define PL (64 * RS)

__device__ __forceinline__ void qmm4(
    const ushort_t* __restrict__ Prm, const ushort_t* __restrict__ Qcm,
    float* ore, float* oim, int mt, int nt, int quad, int l15)
{
  f32x4_t aR = (f32x4_t){0.f, 0.f, 0.f, 0.f};
  f32x4_t aN = (f32x4_t){0.f, 0.f, 0.f, 0.f};
  f32x4_t aI = (f32x4_t){0.f, 0.f, 0.f, 0.f};
#pragma unroll
  for (int kb = 0; kb < 2; ++kb) {
    const int ko = kb * 32 + quad * 8;
    const int ra = (mt * 16 + l15) * RS + ko;
    bf16x8_t arh = *(const bf16x8_t*)&Prm[0 * PL + ra];
    bf16x8_t arl = *(const bf16x8_t*)&Prm[1 * PL + ra];
    bf16x8_t aih = *(const bf16x8_t*)&Prm[2 * PL + ra];
    bf16x8_t ail = *(const bf16x8_t*)&Prm[3 * PL + ra];
    const int rb = (nt * 16 + l15) * RS + ko;
    bf16x8_t brh = *(const bf16x8_t*)&Qcm[0 * PL + rb];
    bf16x8_t brl = *(const bf16x8_t*)&Qcm[1 * PL + rb];
    bf16x8_t bih = *(const bf16x8_t*)&Qcm[2 * PL + rb];
    bf16x8_t bil = *(const bf16x8_t*)&Qcm[3 * PL + rb];
    aR = __builtin_amdgcn_mfma_f32_16x16x32_bf16(arh, brh, aR, 0, 0, 0);
    aR = __builtin_amdgcn_mfma_f32_16x16x32_bf16(arh, brl, aR, 0, 0, 0);
    aR = __builtin_amdgcn_mfma_f32_16x16x32_bf16(arl, brh, aR, 0, 0, 0);
    aN = __builtin_amdgcn_mfma_f32_16x16x32_bf16(aih, bih, aN, 0, 0, 0);
    aN = __builtin_amdgcn_mfma_f32_16x16x32_bf16(aih, bil, aN, 0, 0, 0);
    aN = __builtin_amdgcn_mfma_f32_16x16x32_bf16(ail, bih, aN, 0, 0, 0);
    aI = __builtin_amdgcn_mfma_f32_16x16x32_bf16(arh, bih, aI, 0, 0, 0);
    aI = __builtin_amdgcn_mfma_f32_16x16x32_bf16(arh, bil, aI, 0, 0, 0);
    aI = __builtin_amdgcn_mfma_f32_16x16x32_bf16(arl, bih, aI, 0, 0, 0);
    aI = __builtin_amdgcn_mfma_f32_16x16x32_bf16(aih, brh, aI, 0, 0, 0);
    aI = __builtin_amdgcn_mfma_f32_16x16x32_bf16(aih, brl, aI, 0, 0, 0);
    aI = __builtin_amdgcn_mfma_f32_16x16x32_bf16(ail, brh, aI, 0, 0, 0);
  }
#pragma unroll
  for (int rg = 0; rg < 4; ++rg) {
    ore[rg] = aR[rg] - aN[rg];
    oim[rg] = aI[rg];
  }
}

__device__ __forceinline__ void stage_rm4(
    ushort_t* rm, const float* re, const float* im, int mt, int nt,
    int quad, int l15)
{
  unsigned rh[4], rl[4], ih[4], il[4];
#pragma unroll
  for (int rg = 0; rg < 4; ++rg) {
    tsplit(re[rg], rh[rg], rl[rg]);
    tsplit(im[rg], ih[rg], il[rg]);
  }
#pragma unroll
  for (int rg = 0; rg < 4; ++rg) {
    int idx = (mt * 16 + quad * 4 + rg) * RS + nt * 16 + l15;
    rm[0 * PL + idx] = (ushort_t)rh[rg];
    rm[1 * PL + idx] = (ushort_t)rl[rg];
    rm[2 * PL + idx] = (ushort_t)ih[rg];
    rm[3 * PL + idx] = (ushort_t)il[rg];
  }
}

__device__ __forceinline__ void stage_cm4(
    ushort_t* cm, const float* re, const float* im, int mt, int nt,
    int quad, int l15)
{
  unsigned rh[4], rl[4], ih[4], il[4];
#pragma unroll
  for (int rg = 0; rg < 4; ++rg) {
    tsplit(re[rg], rh[rg], rl[rg]);
    tsplit(im[rg], ih[rg], il[rg]);
  }
  int base = (nt * 16 + l15) * RS + mt * 16 + quad * 4;
  uint2 p;
  p.x = rh[0] | (rh[1] << 16); p.y = rh[2] | (rh[3] << 16);
  *(uint2*)&cm[0 * PL + base] = p;
  p.x = rl[0] | (rl[1] << 16); p.y = rl[2] | (rl[3] << 16);
  *(uint2*)&cm[1 * PL + base] = p;
  p.x = ih[0] | (ih[1] << 16); p.y = ih[2] | (ih[3] << 16);
  *(uint2*)&cm[2 * PL + base] = p;
  p.x = il[0] | (il[1] << 16); p.y = il[2] | (il[3] << 16);
  *(uint2*)&cm[3 * PL + base] = p;
}

__device__ __forceinline__ void stage_both4(
    ushort_t* rm, ushort_t* cm, const float* re, const float* im,
    int mt, int nt, int quad, int l15)
{
  stage_rm4(rm, re, im, mt, nt, quad, l15);
  stage_cm4(cm, re, im, mt, nt, quad, l15);
}

__global__ __launch_bounds__(1024, 4) void quantum_kernel(
    const float* __restrict__ pin,      // fused: part[4][256][4096]; else theta
    const float* __restrict__ b2g,      // [4095] (fused only)
    const float* __restrict__ vp,
    const float* __restrict__ Aobs,
    const float* __restrict__ Bobs,
    const float* __restrict__ Dobs,
    float* __restrict__ out,
    int fused)
{
  __shared__ __align__(16) ushort_t PQ[2][8 * PL];
  __shared__ float ps[128];
  __shared__ float scr16[16];
  __shared__ float csb[24], snb[24];
  __shared__ float sAf;
  __shared__ int   sS;

  float*  thetas = (float*)&PQ[1][0];
  float2* Als    = (float2*)&PQ[0][0];

  const int t = threadIdx.x;
  const int b = blockIdx.x;
  const int lane = t & 63;
  const int w = t >> 6;
  const int quad = lane >> 4;
  const int l15 = lane & 15;
  const int mt = w >> 2, nt = w & 3;

  // ---- 1. load theta (fused: 4-way split-K reduce + bias), Frobenius ----
  float ssq;
  {
    float4 v = ((const float4*)(pin + (size_t)b * 4096))[t];
    if (fused) {
#pragma unroll
      for (int k = 1; k < 4; ++k) {
        float4 u =
            ((const float4*)(pin + (size_t)k * 256 * 4096 + (size_t)b * 4096))[t];
        v.x += u.x; v.y += u.y; v.z += u.z; v.w += u.w;
      }
      int n0i = 4 * t;
      v.x += b2g[n0i];
      v.y += b2g[n0i + 1];
      v.z += b2g[n0i + 2];
      if (n0i + 3 < 4095) v.w += b2g[n0i + 3];
    }
    if (t == 1023) v.w = 0.f;
    thetas[4 * t + 0] = v.x; thetas[4 * t + 1] = v.y;
    thetas[4 * t + 2] = v.z; thetas[4 * t + 3] = v.w;
    ssq = v.x * v.x + v.y * v.y + v.z * v.z + v.w * v.w;
  }
#pragma unroll
  for (int mm = 1; mm < 64; mm <<= 1) ssq += __shfl_xor(ssq, mm);
  if (lane == 0) scr16[w] = ssq;
  __syncthreads();
  if (w == 0) {
    float s = (lane < 16) ? scr16[lane] : 0.f;
#pragma unroll
    for (int mm = 1; mm < 64; mm <<= 1) s += __shfl_xor(s, mm);
    if (lane == 0) {
      float frob = fmaxf(8.f * sqrtf(s), 1e-3f);
      sAf = frob;
      float bound = 0.30f * frob;   // GUE lam_max ~ 0.25 frob + 20% margin
      int sc = (bound > 1.f) ? (int)ceilf(log2f(bound)) : 0;
      sS = sc < 0 ? 0 : (sc > 12 ? 12 : sc);
    }
  } else if (w == 1 && lane < 24) {
    float sn, cs;
    sincosf(vp[lane] * 0.5f, &sn, &cs);
    snb[lane] = sn;
    csb[lane] = cs;
  }
  __syncthreads();
  const int sPow = sS;

  // ---- 2. build A via phase-premultiplied WHT (shfl butterflies) ----
  for (int xx = 0; xx < 4; ++xx) {
    const int x = w + 16 * xx;
    const int z = lane;
    int g1 = 0;
#pragma unroll
    for (int bq = 0; bq < 6; ++bq) {
      int xb = (x >> bq) & 1, zb = (z >> bq) & 1;
      int dig = xb ? (zb ? 2 : 1) : (zb ? 3 : 0);
      g1 |= dig << (2 * bq);
    }
    float tv = (g1 == 0) ? 0.f : thetas[g1 - 1];
    int pc = __popc(x & z) & 3;
    float re, im;
    switch (pc) {
      case 0:  re = tv;  im = 0.f;  break;
      case 1:  re = 0.f; im = -tv;  break;
      case 2:  re = -tv; im = 0.f;  break;
      default: re = 0.f; im = tv;   break;
    }
#pragma unroll
    for (int mk = 1; mk < 64; mk <<= 1) {
      float ore = __shfl_xor(re, mk);
      float oim = __shfl_xor(im, mk);
      if (z & mk) { re = ore - re; im = oim - im; }
      else        { re = re + ore; im = im + oim; }
    }
    Als[z * 66 + (z ^ x)] = make_float2(re, im);
  }
  __syncthreads();

  // ---- 3. B = i * A * 2^-s into per-thread C-ownership registers ----
  const float scl = ldexpf(1.f, -sPow);
  float bre[4], bim[4];
#pragma unroll
  for (int rg = 0; rg < 4; ++rg) {
    int row = mt * 16 + quad * 4 + rg;
    int col = nt * 16 + l15;
    float2 v = Als[row * 66 + col];
    bre[rg] = -v.y * scl;
    bim[rg] =  v.x * scl;
  }
  __syncthreads();

  // ---- 4. Taylor-8 exp(B) via Paterson-Stockmeyer (4 matmuls) ----
  ushort_t* b0 = &PQ[0][0];
  ushort_t* b1 = &PQ[1][0];
  stage_both4(b0, b0 + 4 * PL, bre, bim, mt, nt, quad, l15);
  __syncthreads();
  float b2re[4], b2im[4];
  qmm4(b0, b0 + 4 * PL, b2re, b2im, mt, nt, quad, l15);   // B2 = B*B
  stage_both4(b1, b1 + 4 * PL, b2re, b2im, mt, nt, quad, l15);
  __syncthreads();
  float b3re[4], b3im[4];
  qmm4(b1, b0 + 4 * PL, b3re, b3im, mt, nt, quad, l15);   // B3 = B2*B

  const float c3 = 1.f / 6.f, c4 = 1.f / 24.f, c5 = 1.f / 120.f;
  const float c6 = 1.f / 720.f, c7 = 1.f / 5040.f, c8 = 1.f / 40320.f;
  float s1re[4], s1im[4], p0re[4], p0im[4];
#pragma unroll
  for (int rg = 0; rg < 4; ++rg) {
    float dg = (mt == nt && l15 == quad * 4 + rg) ? 1.f : 0.f;
    s1re[rg] = c4 * dg + c5 * bre[rg] + c6 * b2re[rg] + c7 * b3re[rg];
    s1im[rg] =           c5 * bim[rg] + c6 * b2im[rg] + c7 * b3im[rg];
    p0re[rg] = dg + bre[rg] + 0.5f * b2re[rg] + c3 * b3re[rg];
    p0im[rg] =      bim[rg] + 0.5f * b2im[rg] + c3 * b3im[rg];
  }
  float b4re[4], b4im[4];
  qmm4(b1, b1 + 4 * PL, b4re, b4im, mt, nt, quad, l15);   // B4 = B2*B2
#pragma unroll
  for (int rg = 0; rg < 4; ++rg) {
    s1re[rg] += c8 * b4re[rg];
    s1im[rg] += c8 * b4im[rg];
  }
  __syncthreads();
  stage_rm4(b0, s1re, s1im, mt, nt, quad, l15);
  stage_cm4(b0 + 4 * PL, b4re, b4im, mt, nt, quad, l15);
  __syncthreads();
  float ure[4], uim[4];
  qmm4(b0, b0 + 4 * PL, ure, uim, mt, nt, quad, l15);     // S1*B4
#pragma unroll
  for (int rg = 0; rg < 4; ++rg) {
    ure[rg] += p0re[rg];
    uim[rg] += p0im[rg];
  }

  // ---- 5. s squarings, ping-pong, 1 barrier each ----
  int cur = 1;
  for (int q = 0; q < sPow; ++q) {
    ushort_t* bb = &PQ[cur][0];
    stage_both4(bb, bb + 4 * PL, ure, uim, mt, nt, quad, l15);
    __syncthreads();
    qmm4(bb, bb + 4 * PL, ure, uim, mt, nt, quad, l15);
    cur ^= 1;
  }

  // ---- 6. psi = column 0 of U ----
  if (nt == 0 && l15 == 0) {
#pragma unroll
    for (int rg = 0; rg < 4; ++rg) {
      int row = mt * 16 + quad * 4 + rg;
      ps[2 * row] = ure[rg];
      ps[2 * row + 1] = uim[rg];
    }
  }
  __syncthreads();

  // ---- 7. RY/CNOT circuit via wave shuffles (wave 0) ----
  if (t < 64) {
    float pre = ps[2 * t], pim = ps[2 * t + 1];
#pragma unroll
    for (int d = 0; d < 4; ++d) {
#pragma unroll
      for (int q = 0; q < 6; ++q) {
        float s = snb[d * 6 + q], c = csb[d * 6 + q];
        int bpos = 5 - q;
        int bit = (t >> bpos) & 1;
        float ore = __shfl_xor(pre, 1 << bpos);
        float oim = __shfl_xor(pim, 1 << bpos);
        float sg = bit ? s : -s;
        pre = c * pre + sg * ore;
        pim = c * pim + sg * oim;
      }
#pragma unroll
      for (int q = 0; q < 6; ++q) {
        int bc = 5 - q;
        int bt = 5 - ((q + 1) % 6);
        float ore = __shfl_xor(pre, 1 << bt);
        float oim = __shfl_xor(pim, 1 << bt);
        int ctrl = (t >> bc) & 1;
        pre = ctrl ? ore : pre;
        pim = ctrl ? oim : pim;
      }
    }
    ps[2 * t] = pre; ps[2 * t + 1] = pim;
  }
  __syncthreads();

  // ---- 8. pair terms t_ij = conj(psi_i) psi_j (tril), alias buf0 ----
  float* Rt = (float*)&PQ[0][0];
  float* It = Rt + 2016;
  for (int p = t; p < 2016; p += 1024) {
    int i = (int)((1.f + sqrtf(8.f * (float)p + 1.f)) * 0.5f);
    while (i * (i - 1) / 2 > p) --i;
    while (i * (i + 1) / 2 <= p) ++i;
    int j = p - i * (i - 1) / 2;
    float pri = ps[2 * i], pii = ps[2 * i + 1];
    float prj = ps[2 * j], pij = ps[2 * j + 1];
    Rt[p] = pri * prj + pii * pij;
    It[p] = pri * pij - pii * prj;
  }
  __syncthreads();

  // ---- 9. observables: one obs per wave (waves 0..14) ----
  if (w < 15) {
    float xr = ps[2 * lane], xi = ps[2 * lane + 1];
    float mypsq = xr * xr + xi * xi;
    const float* Ap = Aobs + w * 2016;
    const float* Bp = Bobs + w * 2016;
    float part = 0.f;
    for (int p2 = lane; p2 < 1008; p2 += 64) {
      float2 a = *(const float2*)&Ap[2 * p2];
      float2 bb2 = *(const float2*)&Bp[2 * p2];
      float2 rt = *(const float2*)&Rt[2 * p2];
      float2 it = *(const float2*)&It[2 * p2];
      part += a.x * rt.x - bb2.x * it.x;
      part += a.y * rt.y - bb2.y * it.y;
    }
    if (lane < 63) part += Dobs[w * 64 + lane + 1] * mypsq;
#pragma unroll
    for (int mm = 1; mm < 64; mm <<= 1) part += __shfl_xor(part, mm);
    if (lane == 0) out[b * 15 + w] = 2.f * part;
  }
}

// ---------------- launch ----------------
extern "C" void kernel_launch(void* const* d_in, const int* in_sizes, int n_in,
                              void* d_out, int out_size, void* d_ws, size_t ws_size,
                              hipStream_t stream) {
  const float* x  = (const float*)d_in[0];
  const float* W1 = (const float*)d_in[1];
  const float* b1 = (const float*)d_in[2];
  const float* W2 = (const float*)d_in[3];
  const float* b2 = (const float*)d_in[4];
  const float* vp = (const float*)d_in[5];
  const float* Ao = (const float*)d_in[6];
  const float* Bo = (const float*)d_in[7];
  const float* Do = (const float*)d_in[8];
  float* out = (float*)d_out;

  // Workspace (bytes): part16 [0,16MB), hh [16,17MB), hl [17,18MB).
  const size_t O_PT = 0;            // 16 MB (gemm2 split-K=4 partials)
  const size_t O_HH = 16777216;     // 1 MB
  const size_t O_HL = 17825792;     // 1 MB
  const size_t NEED = 18874368;     // 18 MB

  if (ws_size >= NEED) {
    char* ws = (char*)d_ws;
    float* part16 = (float*)(ws + O_PT);
    ushort_t* hh  = (ushort_t*)(ws + O_HH);
    ushort_t* hl  = (ushort_t*)(ws + O_HL);

    // 1) gemm1: h = silu(x @ W1 + b1); fp32 inputs split/transposed in-stage
    gemm1_kernel<<<256, 512, 0, stream>>>(x, W1, b1, hh, hl);
    // 2) GEMM2: [256x2048] x W2^T, 64m-tile, split-K=4, 2-phase dbuf pipeline
    gemm2k_kernel<<<dim3(64, 4, 4), 256, 0, stream>>>(hh, hl, W2, part16);
    // 3) quantum (fused 4-way reduce + bias)
    quantum_kernel<<<256, 1024, 0, stream>>>(part16, b2, vp, Ao, Bo, Do, out, 1);
  } else {
    float* h     = (float*)d_ws;
    float* theta = h + 256 * 2048;
    gemm_tiled<<<dim3(32, 4), 256, 0, stream>>>(
        x, W1, b1, h, 256, 2047, 1024, 1024, 2047, 2048, 1, 2048);
    gemm_tiled<<<dim3(64, 4), 256, 0, stream>>>(
        h, W2, b2, theta, 256, 4095, 2047, 2048, 4095, 4096, 0, 4096);
    quantum_kernel<<<256, 1024, 0, stream>>>(theta, b2, vp, Ao, Bo, Do, out, 0);
  }
}

// Round 5
// 173.346 us; speedup vs baseline: 1.1568x; 1.1568x over previous
//
#include <hip/hip_runtime.h>
#include <math.h>

typedef unsigned short ushort_t;
typedef __attribute__((ext_vector_type(8))) short bf16x8_t;
typedef __attribute__((ext_vector_type(4))) float f32x4_t;

// ---------------- split helpers ----------------
// Truncation split: hi = trunc16(v), lo = trunc16(v - hi); |err| <= 2^-16 |v|.
__device__ __forceinline__ void tsplit(float v, unsigned& h, unsigned& l) {
  unsigned u = __float_as_uint(v);
  h = u >> 16;
  float lo = v - __uint_as_float(u & 0xffff0000u);
  l = __float_as_uint(lo) >> 16;
}

// split 8 fp32 -> hi/lo bf16x8 fragments (k-contiguous packing)
__device__ __forceinline__ void split8(const float* p, bf16x8_t& hi, bf16x8_t& lo) {
#pragma unroll
  for (int e = 0; e < 8; ++e) {
    unsigned h, l;
    tsplit(p[e], h, l);
    hi[e] = (short)h;
    lo[e] = (short)l;
  }
}

#define LSTR 40

// ---------------- gemm1: h = silu(x @ W1 + b1) -> hh/hl ----------------
// R1-proven structure: 512 threads, 8 waves (2m x 4n of 16x16), tile 32m x
// 64n, K=1024, BK=32. Staging splits/transposes fp32 inputs in registers:
//   waves 0-1: x tile, waves 2-5: W1 tile (coalesced across 64 n per instr),
//   waves 6-7: idle during stage. No reg-prefetch.
__global__ __launch_bounds__(512) void gemm1_kernel(
    const float* __restrict__ x, const float* __restrict__ W1,
    const float* __restrict__ b1,
    ushort_t* __restrict__ hh, ushort_t* __restrict__ hl) {
  __shared__ __align__(16) ushort_t As[2][32 * LSTR];
  __shared__ __align__(16) ushort_t Bs[2][64 * LSTR];
  const int t = threadIdx.x;
  const int lane = t & 63;
  const int wv = t >> 6;          // 0..7
  const int l15 = lane & 15;
  const int quad = lane >> 4;
  const int wm = wv & 1;          // m half (16 rows)
  const int wn = wv >> 1;         // n strip (16 cols)
  const int m0 = (blockIdx.x >> 5) * 32;
  const int n0 = (blockIdx.x & 31) * 64;

  f32x4_t acc = (f32x4_t){0.f, 0.f, 0.f, 0.f};

  // staging roles
  const int xrow = (t & 127) >> 2;     // waves 0-1: 32 rows
  const int xkq  = (t & 3) * 8;        // 8 consecutive k
  const int wu   = t - 128;            // waves 2-5: W1
  const int wnx  = wu & 63;            // n within tile
  const int wkh  = (wu >> 6) & 3;      // k-octet 0..3
  const bool wok = (n0 + wnx) < 2047;

  for (int k0 = 0; k0 < 1024; k0 += 32) {
    if (t < 128) {
      const float* src = x + (size_t)(m0 + xrow) * 1024 + k0 + xkq;
      float p[8];
      float4 va = *(const float4*)src;
      float4 vb = *(const float4*)(src + 4);
      p[0] = va.x; p[1] = va.y; p[2] = va.z; p[3] = va.w;
      p[4] = vb.x; p[5] = vb.y; p[6] = vb.z; p[7] = vb.w;
      bf16x8_t hi, lo;
      split8(p, hi, lo);
      *(bf16x8_t*)&As[0][xrow * LSTR + xkq] = hi;
      *(bf16x8_t*)&As[1][xrow * LSTR + xkq] = lo;
    } else if (t < 384) {
      float p[8];
#pragma unroll
      for (int i = 0; i < 8; ++i) {
        int k = k0 + wkh * 8 + i;     // k < 1024 always
        p[i] = wok ? W1[(size_t)k * 2047 + n0 + wnx] : 0.f;
      }
      bf16x8_t hi, lo;
      split8(p, hi, lo);
      *(bf16x8_t*)&Bs[0][wnx * LSTR + wkh * 8] = hi;
      *(bf16x8_t*)&Bs[1][wnx * LSTR + wkh * 8] = lo;
    }
    __syncthreads();
    const int nr = wn * 16 + l15;
    bf16x8_t bfh = *(const bf16x8_t*)&Bs[0][nr * LSTR + quad * 8];
    bf16x8_t bfl = *(const bf16x8_t*)&Bs[1][nr * LSTR + quad * 8];
    const int mr = wm * 16 + l15;
    bf16x8_t afh = *(const bf16x8_t*)&As[0][mr * LSTR + quad * 8];
    bf16x8_t afl = *(const bf16x8_t*)&As[1][mr * LSTR + quad * 8];
    acc = __builtin_amdgcn_mfma_f32_16x16x32_bf16(afh, bfh, acc, 0, 0, 0);
    acc = __builtin_amdgcn_mfma_f32_16x16x32_bf16(afh, bfl, acc, 0, 0, 0);
    acc = __builtin_amdgcn_mfma_f32_16x16x32_bf16(afl, bfh, acc, 0, 0, 0);
    __syncthreads();
  }
  // epilogue: bias + silu + split -> hh/hl (col 2047 = 0 pad)
  const int col = n0 + wn * 16 + l15;
#pragma unroll
  for (int rg = 0; rg < 4; ++rg) {
    int row = m0 + wm * 16 + quad * 4 + rg;
    float v = acc[rg];
    if (col < 2047) {
      v += b1[col];
      v = v / (1.f + expf(-v));
    } else {
      v = 0.f;
    }
    unsigned h, l;
    tsplit(v, h, l);
    size_t o = (size_t)row * 2048 + col;
    hh[o] = (ushort_t)h;
    hl[o] = (ushort_t)l;
  }
}

// ---------------- GEMM2: 64m x 64n tile, split-K=8, BK=32 ----------------
// R5 changes vs R3: (a) split-K 4 -> 8: grid 2048 blocks = 8 blocks/CU
// (20 KB LDS x 8 = 160 KiB, 2048 threads = 100% occupancy) for TLP latency
// hiding -- the lever R3's win isolated; (b) staging merged across all 4
// waves: every thread stages A (2x int4) AND W2 (8 scalars), doubling the
// wave-parallel issue width on the W2 load stream. LDS layout, fragment
// reads and per-slice MFMA order identical to R3.
__global__ __launch_bounds__(256) void gemm2k_kernel(
    const ushort_t* __restrict__ Ah, const ushort_t* __restrict__ Al,
    const float* __restrict__ W2,
    float* __restrict__ part) {
  __shared__ __align__(16) ushort_t Ab[2][64 * LSTR];
  __shared__ __align__(16) ushort_t Bb[2][64 * LSTR];
  const int t = threadIdx.x;
  const int lane = t & 63;
  const int wv = t >> 6;
  const int l15 = lane & 15;
  const int quad = lane >> 4;
  const int wm = wv >> 1, wn = wv & 1;
  const int m0 = blockIdx.y * 64;
  const int n0 = blockIdx.x * 64;
  const int ks = blockIdx.z;

  // merged staging roles (all 256 threads)
  const int ar  = t >> 2;           // A: row 0..63
  const int ac  = (t & 3) * 8;      // A: 8-ushort chunk
  const int bn  = t & 63;           // B: n within tile
  const int bko = (t >> 6) * 8;     // B: k-octet 0..3
  const bool bok = (n0 + bn) < 4095;

  f32x4_t acc[2][2];
#pragma unroll
  for (int i = 0; i < 2; ++i)
#pragma unroll
    for (int j = 0; j < 2; ++j) acc[i][j] = (f32x4_t){0.f, 0.f, 0.f, 0.f};

  for (int kt = 0; kt < 8; ++kt) {
    const int k0 = ks * 256 + kt * 32;
    // A: both planes, 2 int4 per thread
    *(int4*)&Ab[0][ar * LSTR + ac] =
        *(const int4*)(Ah + (size_t)(m0 + ar) * 2048 + k0 + ac);
    *(int4*)&Ab[1][ar * LSTR + ac] =
        *(const int4*)(Al + (size_t)(m0 + ar) * 2048 + k0 + ac);
    // B: 8 W2 scalars per thread, split in regs
    {
      float p[8];
#pragma unroll
      for (int e = 0; e < 8; ++e) {
        int k = k0 + bko + e;
        p[e] = (bok && k < 2047) ? W2[(size_t)k * 4095 + n0 + bn] : 0.f;
      }
      bf16x8_t hi, lo;
      split8(p, hi, lo);
      *(bf16x8_t*)&Bb[0][bn * LSTR + bko] = hi;
      *(bf16x8_t*)&Bb[1][bn * LSTR + bko] = lo;
    }
    __syncthreads();
    bf16x8_t bfh[2], bfl[2];
#pragma unroll
    for (int j = 0; j < 2; ++j) {
      int nr = wn * 32 + j * 16 + l15;
      bfh[j] = *(const bf16x8_t*)&Bb[0][nr * LSTR + quad * 8];
      bfl[j] = *(const bf16x8_t*)&Bb[1][nr * LSTR + quad * 8];
    }
#pragma unroll
    for (int i = 0; i < 2; ++i) {
      int mr = wm * 32 + i * 16 + l15;
      bf16x8_t afh = *(const bf16x8_t*)&Ab[0][mr * LSTR + quad * 8];
      bf16x8_t afl = *(const bf16x8_t*)&Ab[1][mr * LSTR + quad * 8];
#pragma unroll
      for (int j = 0; j < 2; ++j) {
        acc[i][j] = __builtin_amdgcn_mfma_f32_16x16x32_bf16(
            afh, bfh[j], acc[i][j], 0, 0, 0);
        acc[i][j] = __builtin_amdgcn_mfma_f32_16x16x32_bf16(
            afh, bfl[j], acc[i][j], 0, 0, 0);
        acc[i][j] = __builtin_amdgcn_mfma_f32_16x16x32_bf16(
            afl, bfh[j], acc[i][j], 0, 0, 0);
      }
    }
    __syncthreads();
  }
  float* pbase = part + (size_t)ks * 256 * 4096;
#pragma unroll
  for (int i = 0; i < 2; ++i)
#pragma unroll
    for (int j = 0; j < 2; ++j) {
      int row0 = m0 + wm * 32 + i * 16 + quad * 4;
      int col = n0 + wn * 32 + j * 16 + l15;
#pragma unroll
      for (int rg = 0; rg < 4; ++rg)
        pbase[(size_t)(row0 + rg) * 4096 + col] = acc[i][j][rg];
    }
}

// ---------------- fallback fp32 GEMM (round-1, known-good) ----------------
#define TM 64
#define TN 64
#define TK 16
__global__ __launch_bounds__(256) void gemm_tiled(
    const float* __restrict__ X, const float* __restrict__ W,
    const float* __restrict__ bias, float* __restrict__ out,
    int M, int N, int K, int ldx, int ldw, int ldo, int doSilu, int padN)
{
  __shared__ float Xs[TK][TM + 4];
  __shared__ float Ws[TK][TN + 4];
  const int t = threadIdx.x;
  const int n0 = blockIdx.x * TN;
  const int m0 = blockIdx.y * TM;
  const int tr = t >> 4, tc = t & 15;
  float acc[4][4];
#pragma unroll
  for (int i = 0; i < 4; ++i)
#pragma unroll
    for (int j = 0; j < 4; ++j) acc[i][j] = 0.f;
  const int xr = t >> 2, xk = (t & 3) * 4;
  const int wk = t >> 4, wc = (t & 15) * 4;
  for (int k0 = 0; k0 < K; k0 += TK) {
    {
      const float* xp = X + (size_t)(m0 + xr) * ldx + (k0 + xk);
      float xv[4];
      if (k0 + xk + 3 < K) {
        float4 v = *(const float4*)xp;
        xv[0] = v.x; xv[1] = v.y; xv[2] = v.z; xv[3] = v.w;
      } else {
#pragma unroll
        for (int e = 0; e < 4; ++e) xv[e] = (k0 + xk + e < K) ? xp[e] : 0.f;
      }
#pragma unroll
      for (int e = 0; e < 4; ++e) Xs[xk + e][xr] = xv[e];
    }
    {
      const int kk = k0 + wk;
      const float* wp = W + (size_t)kk * ldw + (n0 + wc);
      const bool kv = kk < K;
#pragma unroll
      for (int e = 0; e < 4; ++e) {
        int n = n0 + wc + e;
        Ws[wk][wc + e] = (kv && n < N) ? wp[e] : 0.f;
      }
    }
    __syncthreads();
#pragma unroll
    for (int k = 0; k < TK; ++k) {
      float4 av = *(const float4*)&Xs[k][tr * 4];
      float4 bv = *(const float4*)&Ws[k][tc * 4];
      float a4[4] = {av.x, av.y, av.z, av.w};
      float b4[4] = {bv.x, bv.y, bv.z, bv.w};
#pragma unroll
      for (int i = 0; i < 4; ++i)
#pragma unroll
        for (int j = 0; j < 4; ++j)
          acc[i][j] = fmaf(a4[i], b4[j], acc[i][j]);
    }
    __syncthreads();
  }
#pragma unroll
  for (int i = 0; i < 4; ++i) {
    const int mrow = m0 + tr * 4 + i;
    float* op = out + (size_t)mrow * ldo;
#pragma unroll
    for (int j = 0; j < 4; ++j) {
      const int n = n0 + tc * 4 + j;
      if (n < N) {
        float v = acc[i][j] + bias[n];
        if (doSilu) v = v / (1.f + expf(-v));
        op[n] = v;
      } else if (n < padN) {
        op[n] = 0.f;
      }
    }
  }
}

// ---------------- quantum pipeline: 1024 threads, 16 waves, 1 tile/wave ----
#define RS 72
#define PL (64 * RS)

__device__ __forceinline__ void qmm4(
    const ushort_t* __restrict__ Prm, const ushort_t* __restrict__ Qcm,
    float* ore, float* oim, int mt, int nt, int quad, int l15)
{
  f32x4_t aR = (f32x4_t){0.f, 0.f, 0.f, 0.f};
  f32x4_t aN = (f32x4_t){0.f, 0.f, 0.f, 0.f};
  f32x4_t aI = (f32x4_t){0.f, 0.f, 0.f, 0.f};
#pragma unroll
  for (int kb = 0; kb < 2; ++kb) {
    const int ko = kb * 32 + quad * 8;
    const int ra = (mt * 16 + l15) * RS + ko;
    bf16x8_t arh = *(const bf16x8_t*)&Prm[0 * PL + ra];
    bf16x8_t arl = *(const bf16x8_t*)&Prm[1 * PL + ra];
    bf16x8_t aih = *(const bf16x8_t*)&Prm[2 * PL + ra];
    bf16x8_t ail = *(const bf16x8_t*)&Prm[3 * PL + ra];
    const int rb = (nt * 16 + l15) * RS + ko;
    bf16x8_t brh = *(const bf16x8_t*)&Qcm[0 * PL + rb];
    bf16x8_t brl = *(const bf16x8_t*)&Qcm[1 * PL + rb];
    bf16x8_t bih = *(const bf16x8_t*)&Qcm[2 * PL + rb];
    bf16x8_t bil = *(const bf16x8_t*)&Qcm[3 * PL + rb];
    aR = __builtin_amdgcn_mfma_f32_16x16x32_bf16(arh, brh, aR, 0, 0, 0);
    aR = __builtin_amdgcn_mfma_f32_16x16x32_bf16(arh, brl, aR, 0, 0, 0);
    aR = __builtin_amdgcn_mfma_f32_16x16x32_bf16(arl, brh, aR, 0, 0, 0);
    aN = __builtin_amdgcn_mfma_f32_16x16x32_bf16(aih, bih, aN, 0, 0, 0);
    aN = __builtin_amdgcn_mfma_f32_16x16x32_bf16(aih, bil, aN, 0, 0, 0);
    aN = __builtin_amdgcn_mfma_f32_16x16x32_bf16(ail, bih, aN, 0, 0, 0);
    aI = __builtin_amdgcn_mfma_f32_16x16x32_bf16(arh, bih, aI, 0, 0, 0);
    aI = __builtin_amdgcn_mfma_f32_16x16x32_bf16(arh, bil, aI, 0, 0, 0);
    aI = __builtin_amdgcn_mfma_f32_16x16x32_bf16(arl, bih, aI, 0, 0, 0);
    aI = __builtin_amdgcn_mfma_f32_16x16x32_bf16(aih, brh, aI, 0, 0, 0);
    aI = __builtin_amdgcn_mfma_f32_16x16x32_bf16(aih, brl, aI, 0, 0, 0);
    aI = __builtin_amdgcn_mfma_f32_16x16x32_bf16(ail, brh, aI, 0, 0, 0);
  }
#pragma unroll
  for (int rg = 0; rg < 4; ++rg) {
    ore[rg] = aR[rg] - aN[rg];
    oim[rg] = aI[rg];
  }
}

__device__ __forceinline__ void stage_rm4(
    ushort_t* rm, const float* re, const float* im, int mt, int nt,
    int quad, int l15)
{
  unsigned rh[4], rl[4], ih[4], il[4];
#pragma unroll
  for (int rg = 0; rg < 4; ++rg) {
    tsplit(re[rg], rh[rg], rl[rg]);
    tsplit(im[rg], ih[rg], il[rg]);
  }
#pragma unroll
  for (int rg = 0; rg < 4; ++rg) {
    int idx = (mt * 16 + quad * 4 + rg) * RS + nt * 16 + l15;
    rm[0 * PL + idx] = (ushort_t)rh[rg];
    rm[1 * PL + idx] = (ushort_t)rl[rg];
    rm[2 * PL + idx] = (ushort_t)ih[rg];
    rm[3 * PL + idx] = (ushort_t)il[rg];
  }
}

__device__ __forceinline__ void stage_cm4(
    ushort_t* cm, const float* re, const float* im, int mt, int nt,
    int quad, int l15)
{
  unsigned rh[4], rl[4], ih[4], il[4];
#pragma unroll
  for (int rg = 0; rg < 4; ++rg) {
    tsplit(re[rg], rh[rg], rl[rg]);
    tsplit(im[rg], ih[rg], il[rg]);
  }
  int base = (nt * 16 + l15) * RS + mt * 16 + quad * 4;
  uint2 p;
  p.x = rh[0] | (rh[1] << 16); p.y = rh[2] | (rh[3] << 16);
  *(uint2*)&cm[0 * PL + base] = p;
  p.x = rl[0] | (rl[1] << 16); p.y = rl[2] | (rl[3] << 16);
  *(uint2*)&cm[1 * PL + base] = p;
  p.x = ih[0] | (ih[1] << 16); p.y = ih[2] | (ih[3] << 16);
  *(uint2*)&cm[2 * PL + base] = p;
  p.x = il[0] | (il[1] << 16); p.y = il[2] | (il[3] << 16);
  *(uint2*)&cm[3 * PL + base] = p;
}

__device__ __forceinline__ void stage_both4(
    ushort_t* rm, ushort_t* cm, const float* re, const float* im,
    int mt, int nt, int quad, int l15)
{
  stage_rm4(rm, re, im, mt, nt, quad, l15);
  stage_cm4(cm, re, im, mt, nt, quad, l15);
}

__global__ __launch_bounds__(1024, 4) void quantum_kernel(
    const float* __restrict__ pin,      // fused: part[8][256][4096]; else theta
    const float* __restrict__ b2g,      // [4095] (fused only)
    const float* __restrict__ vp,
    const float* __restrict__ Aobs,
    const float* __restrict__ Bobs,
    const float* __restrict__ Dobs,
    float* __restrict__ out,
    int fused)
{
  __shared__ __align__(16) ushort_t PQ[2][8 * PL];
  __shared__ float ps[128];
  __shared__ float scr16[16];
  __shared__ float csb[24], snb[24];
  __shared__ float sAf;
  __shared__ int   sS;

  float*  thetas = (float*)&PQ[1][0];
  float2* Als    = (float2*)&PQ[0][0];

  const int t = threadIdx.x;
  const int b = blockIdx.x;
  const int lane = t & 63;
  const int w = t >> 6;
  const int quad = lane >> 4;
  const int l15 = lane & 15;
  const int mt = w >> 2, nt = w & 3;

  // ---- 1. load theta (fused: 8-way split-K reduce + bias), Frobenius ----
  float ssq;
  {
    float4 v = ((const float4*)(pin + (size_t)b * 4096))[t];
    if (fused) {
#pragma unroll
      for (int k = 1; k < 8; ++k) {
        float4 u =
            ((const float4*)(pin + (size_t)k * 256 * 4096 + (size_t)b * 4096))[t];
        v.x += u.x; v.y += u.y; v.z += u.z; v.w += u.w;
      }
      int n0i = 4 * t;
      v.x += b2g[n0i];
      v.y += b2g[n0i + 1];
      v.z += b2g[n0i + 2];
      if (n0i + 3 < 4095) v.w += b2g[n0i + 3];
    }
    if (t == 1023) v.w = 0.f;
    thetas[4 * t + 0] = v.x; thetas[4 * t + 1] = v.y;
    thetas[4 * t + 2] = v.z; thetas[4 * t + 3] = v.w;
    ssq = v.x * v.x + v.y * v.y + v.z * v.z + v.w * v.w;
  }
#pragma unroll
  for (int mm = 1; mm < 64; mm <<= 1) ssq += __shfl_xor(ssq, mm);
  if (lane == 0) scr16[w] = ssq;
  __syncthreads();
  if (w == 0) {
    float s = (lane < 16) ? scr16[lane] : 0.f;
#pragma unroll
    for (int mm = 1; mm < 64; mm <<= 1) s += __shfl_xor(s, mm);
    if (lane == 0) {
      float frob = fmaxf(8.f * sqrtf(s), 1e-3f);
      sAf = frob;
      float bound = 0.30f * frob;   // GUE lam_max ~ 0.25 frob + 20% margin
      int sc = (bound > 1.f) ? (int)ceilf(log2f(bound)) : 0;
      sS = sc < 0 ? 0 : (sc > 12 ? 12 : sc);
    }
  } else if (w == 1 && lane < 24) {
    float sn, cs;
    sincosf(vp[lane] * 0.5f, &sn, &cs);
    snb[lane] = sn;
    csb[lane] = cs;
  }
  __syncthreads();
  const int sPow = sS;

  // ---- 2. build A via phase-premultiplied WHT (shfl butterflies) ----
  for (int xx = 0; xx < 4; ++xx) {
    const int x = w + 16 * xx;
    const int z = lane;
    int g1 = 0;
#pragma unroll
    for (int bq = 0; bq < 6; ++bq) {
      int xb = (x >> bq) & 1, zb = (z >> bq) & 1;
      int dig = xb ? (zb ? 2 : 1) : (zb ? 3 : 0);
      g1 |= dig << (2 * bq);
    }
    float tv = (g1 == 0) ? 0.f : thetas[g1 - 1];
    int pc = __popc(x & z) & 3;
    float re, im;
    switch (pc) {
      case 0:  re = tv;  im = 0.f;  break;
      case 1:  re = 0.f; im = -tv;  break;
      case 2:  re = -tv; im = 0.f;  break;
      default: re = 0.f; im = tv;   break;
    }
#pragma unroll
    for (int mk = 1; mk < 64; mk <<= 1) {
      float ore = __shfl_xor(re, mk);
      float oim = __shfl_xor(im, mk);
      if (z & mk) { re = ore - re; im = oim - im; }
      else        { re = re + ore; im = im + oim; }
    }
    Als[z * 66 + (z ^ x)] = make_float2(re, im);
  }
  __syncthreads();

  // ---- 3. B = i * A * 2^-s into per-thread C-ownership registers ----
  const float scl = ldexpf(1.f, -sPow);
  float bre[4], bim[4];
#pragma unroll
  for (int rg = 0; rg < 4; ++rg) {
    int row = mt * 16 + quad * 4 + rg;
    int col = nt * 16 + l15;
    float2 v = Als[row * 66 + col];
    bre[rg] = -v.y * scl;
    bim[rg] =  v.x * scl;
  }
  __syncthreads();

  // ---- 4. Taylor-8 exp(B) via Paterson-Stockmeyer (4 matmuls) ----
  ushort_t* b0 = &PQ[0][0];
  ushort_t* b1 = &PQ[1][0];
  stage_both4(b0, b0 + 4 * PL, bre, bim, mt, nt, quad, l15);
  __syncthreads();
  float b2re[4], b2im[4];
  qmm4(b0, b0 + 4 * PL, b2re, b2im, mt, nt, quad, l15);   // B2 = B*B
  stage_both4(b1, b1 + 4 * PL, b2re, b2im, mt, nt, quad, l15);
  __syncthreads();
  float b3re[4], b3im[4];
  qmm4(b1, b0 + 4 * PL, b3re, b3im, mt, nt, quad, l15);   // B3 = B2*B

  const float c3 = 1.f / 6.f, c4 = 1.f / 24.f, c5 = 1.f / 120.f;
  const float c6 = 1.f / 720.f, c7 = 1.f / 5040.f, c8 = 1.f / 40320.f;
  float s1re[4], s1im[4], p0re[4], p0im[4];
#pragma unroll
  for (int rg = 0; rg < 4; ++rg) {
    float dg = (mt == nt && l15 == quad * 4 + rg) ? 1.f : 0.f;
    s1re[rg] = c4 * dg + c5 * bre[rg] + c6 * b2re[rg] + c7 * b3re[rg];
    s1im[rg] =           c5 * bim[rg] + c6 * b2im[rg] + c7 * b3im[rg];
    p0re[rg] = dg + bre[rg] + 0.5f * b2re[rg] + c3 * b3re[rg];
    p0im[rg] =      bim[rg] + 0.5f * b2im[rg] + c3 * b3im[rg];
  }
  float b4re[4], b4im[4];
  qmm4(b1, b1 + 4 * PL, b4re, b4im, mt, nt, quad, l15);   // B4 = B2*B2
#pragma unroll
  for (int rg = 0; rg < 4; ++rg) {
    s1re[rg] += c8 * b4re[rg];
    s1im[rg] += c8 * b4im[rg];
  }
  __syncthreads();
  stage_rm4(b0, s1re, s1im, mt, nt, quad, l15);
  stage_cm4(b0 + 4 * PL, b4re, b4im, mt, nt, quad, l15);
  __syncthreads();
  float ure[4], uim[4];
  qmm4(b0, b0 + 4 * PL, ure, uim, mt, nt, quad, l15);     // S1*B4
#pragma unroll
  for (int rg = 0; rg < 4; ++rg) {
    ure[rg] += p0re[rg];
    uim[rg] += p0im[rg];
  }

  // ---- 5. s squarings, ping-pong, 1 barrier each ----
  int cur = 1;
  for (int q = 0; q < sPow; ++q) {
    ushort_t* bb = &PQ[cur][0];
    stage_both4(bb, bb + 4 * PL, ure, uim, mt, nt, quad, l15);
    __syncthreads();
    qmm4(bb, bb + 4 * PL, ure, uim, mt, nt, quad, l15);
    cur ^= 1;
  }

  // ---- 6. psi = column 0 of U ----
  if (nt == 0 && l15 == 0) {
#pragma unroll
    for (int rg = 0; rg < 4; ++rg) {
      int row = mt * 16 + quad * 4 + rg;
      ps[2 * row] = ure[rg];
      ps[2 * row + 1] = uim[rg];
    }
  }
  __syncthreads();

  // ---- 7. RY/CNOT circuit via wave shuffles (wave 0) ----
  if (t < 64) {
    float pre = ps[2 * t], pim = ps[2 * t + 1];
#pragma unroll
    for (int d = 0; d < 4; ++d) {
#pragma unroll
      for (int q = 0; q < 6; ++q) {
        float s = snb[d * 6 + q], c = csb[d * 6 + q];
        int bpos = 5 - q;
        int bit = (t >> bpos) & 1;
        float ore = __shfl_xor(pre, 1 << bpos);
        float oim = __shfl_xor(pim, 1 << bpos);
        float sg = bit ? s : -s;
        pre = c * pre + sg * ore;
        pim = c * pim + sg * oim;
      }
#pragma unroll
      for (int q = 0; q < 6; ++q) {
        int bc = 5 - q;
        int bt = 5 - ((q + 1) % 6);
        float ore = __shfl_xor(pre, 1 << bt);
        float oim = __shfl_xor(pim, 1 << bt);
        int ctrl = (t >> bc) & 1;
        pre = ctrl ? ore : pre;
        pim = ctrl ? oim : pim;
      }
    }
    ps[2 * t] = pre; ps[2 * t + 1] = pim;
  }
  __syncthreads();

  // ---- 8. pair terms t_ij = conj(psi_i) psi_j (tril), alias buf0 ----
  float* Rt = (float*)&PQ[0][0];
  float* It = Rt + 2016;
  for (int p = t; p < 2016; p += 1024) {
    int i = (int)((1.f + sqrtf(8.f * (float)p + 1.f)) * 0.5f);
    while (i * (i - 1) / 2 > p) --i;
    while (i * (i + 1) / 2 <= p) ++i;
    int j = p - i * (i - 1) / 2;
    float pri = ps[2 * i], pii = ps[2 * i + 1];
    float prj = ps[2 * j], pij = ps[2 * j + 1];
    Rt[p] = pri * prj + pii * pij;
    It[p] = pri * pij - pii * prj;
  }
  __syncthreads();

  // ---- 9. observables: one obs per wave (waves 0..14) ----
  if (w < 15) {
    float xr = ps[2 * lane], xi = ps[2 * lane + 1];
    float mypsq = xr * xr + xi * xi;
    const float* Ap = Aobs + w * 2016;
    const float* Bp = Bobs + w * 2016;
    float part = 0.f;
    for (int p2 = lane; p2 < 1008; p2 += 64) {
      float2 a = *(const float2*)&Ap[2 * p2];
      float2 bb2 = *(const float2*)&Bp[2 * p2];
      float2 rt = *(const float2*)&Rt[2 * p2];
      float2 it = *(const float2*)&It[2 * p2];
      part += a.x * rt.x - bb2.x * it.x;
      part += a.y * rt.y - bb2.y * it.y;
    }
    if (lane < 63) part += Dobs[w * 64 + lane + 1] * mypsq;
#pragma unroll
    for (int mm = 1; mm < 64; mm <<= 1) part += __shfl_xor(part, mm);
    if (lane == 0) out[b * 15 + w] = 2.f * part;
  }
}

// ---------------- launch ----------------
extern "C" void kernel_launch(void* const* d_in, const int* in_sizes, int n_in,
                              void* d_out, int out_size, void* d_ws, size_t ws_size,
                              hipStream_t stream) {
  const float* x  = (const float*)d_in[0];
  const float* W1 = (const float*)d_in[1];
  const float* b1 = (const float*)d_in[2];
  const float* W2 = (const float*)d_in[3];
  const float* b2 = (const float*)d_in[4];
  const float* vp = (const float*)d_in[5];
  const float* Ao = (const float*)d_in[6];
  const float* Bo = (const float*)d_in[7];
  const float* Do = (const float*)d_in[8];
  float* out = (float*)d_out;

  // Workspace (bytes): part16 [0,32MB), hh [32,33MB), hl [33,34MB).
  const size_t O_PT = 0;            // 32 MB (gemm2 split-K=8 partials)
  const size_t O_HH = 33554432;     // 1 MB
  const size_t O_HL = 34603008;     // 1 MB
  const size_t NEED = 35651584;     // 34 MB

  if (ws_size >= NEED) {
    char* ws = (char*)d_ws;
    float* part16 = (float*)(ws + O_PT);
    ushort_t* hh  = (ushort_t*)(ws + O_HH);
    ushort_t* hl  = (ushort_t*)(ws + O_HL);

    // 1) gemm1: h = silu(x @ W1 + b1); fp32 inputs split/transposed in-stage
    gemm1_kernel<<<256, 512, 0, stream>>>(x, W1, b1, hh, hl);
    // 2) GEMM2: [256x2048] x W2^T, 64m-tile, split-K=8 (2048 blocks, 8/CU)
    gemm2k_kernel<<<dim3(64, 4, 8), 256, 0, stream>>>(hh, hl, W2, part16);
    // 3) quantum (fused 8-way reduce + bias)
    quantum_kernel<<<256, 1024, 0, stream>>>(part16, b2, vp, Ao, Bo, Do, out, 1);
  } else {
    float* h     = (float*)d_ws;
    float* theta = h + 256 * 2048;
    gemm_tiled<<<dim3(32, 4), 256, 0, stream>>>(
        x, W1, b1, h, 256, 2047, 1024, 1024, 2047, 2048, 1, 2048);
    gemm_tiled<<<dim3(64, 4), 256, 0, stream>>>(
        h, W2, b2, theta, 256, 4095, 2047, 2048, 4095, 4096, 0, 4096);
    quantum_kernel<<<256, 1024, 0, stream>>>(theta, b2, vp, Ao, Bo, Do, out, 0);
  }
}